// Round 1
// baseline (701.554 us; speedup 1.0000x reference)
//
#include <hip/hip_runtime.h>

#define NN 20000
#define KNEI 32
#define DIM 256
#define NHEAD 8
#define HDIM 32
#define DFFN 1024

// ---------------- fp32 tiled GEMM: C[M,Nc] = A[M,Kc] @ B[Kc,Nc] + bias ----------------
template<int RELU>
__global__ __launch_bounds__(256) void gemm_bias(const float* __restrict__ A,
                                                 const float* __restrict__ B,
                                                 const float* __restrict__ bias,
                                                 float* __restrict__ C,
                                                 int M, int Nc, int Kc)
{
    __shared__ float As[16][68];   // As[k][m], padded: 68*4=272B row stride (16B aligned)
    __shared__ float Bs[16][68];   // Bs[k][n]

    const int bm = blockIdx.y * 64;
    const int bn = blockIdx.x * 64;
    const int tid = threadIdx.x;

    const int tm = (tid >> 4) * 4;        // 0..60
    const int tn = (tid & 15) * 4;        // 0..60

    // A-tile loader: thread -> (row lm 0..63, k-quad lk 0..12)
    const int lm = tid >> 2;
    const int lk = (tid & 3) * 4;
    // B-tile loader: thread -> (k row 0..15, col-quad 0..60)
    const int lbk = tid >> 4;
    const int lbn = (tid & 15) * 4;

    int arow = bm + lm;
    if (arow >= M) arow = M - 1;          // clamp; results discarded on store
    const float* Aptr = A + (size_t)arow * Kc + lk;
    const float* Bptr = B + (size_t)lbk * Nc + bn + lbn;

    float acc[4][4] = {};

    for (int k0 = 0; k0 < Kc; k0 += 16) {
        float4 a4 = *(const float4*)(Aptr + k0);
        float4 b4 = *(const float4*)(Bptr + (size_t)k0 * Nc);
        As[lk + 0][lm] = a4.x;
        As[lk + 1][lm] = a4.y;
        As[lk + 2][lm] = a4.z;
        As[lk + 3][lm] = a4.w;
        *(float4*)&Bs[lbk][lbn] = b4;
        __syncthreads();

        #pragma unroll
        for (int kk = 0; kk < 16; ++kk) {
            float a0 = As[kk][tm + 0], a1 = As[kk][tm + 1];
            float a2 = As[kk][tm + 2], a3 = As[kk][tm + 3];
            float b0 = Bs[kk][tn + 0], b1 = Bs[kk][tn + 1];
            float b2 = Bs[kk][tn + 2], b3 = Bs[kk][tn + 3];
            acc[0][0] += a0 * b0; acc[0][1] += a0 * b1; acc[0][2] += a0 * b2; acc[0][3] += a0 * b3;
            acc[1][0] += a1 * b0; acc[1][1] += a1 * b1; acc[1][2] += a1 * b2; acc[1][3] += a1 * b3;
            acc[2][0] += a2 * b0; acc[2][1] += a2 * b1; acc[2][2] += a2 * b2; acc[2][3] += a2 * b3;
            acc[3][0] += a3 * b0; acc[3][1] += a3 * b1; acc[3][2] += a3 * b2; acc[3][3] += a3 * b3;
        }
        __syncthreads();
    }

    float4 bb = *(const float4*)(bias + bn + tn);
    #pragma unroll
    for (int i = 0; i < 4; ++i) {
        int row = bm + tm + i;
        if (row < M) {
            float4 ov;
            ov.x = acc[i][0] + bb.x;
            ov.y = acc[i][1] + bb.y;
            ov.z = acc[i][2] + bb.z;
            ov.w = acc[i][3] + bb.w;
            if (RELU) {
                ov.x = fmaxf(ov.x, 0.f); ov.y = fmaxf(ov.y, 0.f);
                ov.z = fmaxf(ov.z, 0.f); ov.w = fmaxf(ov.w, 0.f);
            }
            *(float4*)(C + (size_t)row * Nc + bn + tn) = ov;
        }
    }
}

// ---------------- attention: per (node, head), one wave ----------------
// q,k,v: [NN, DIM] projected for ALL nodes (gather-after-project == project-after-gather, linear)
__global__ __launch_bounds__(256) void attn_kernel(const float* __restrict__ q,
                                                   const float* __restrict__ k,
                                                   const float* __restrict__ v,
                                                   const int* __restrict__ samp,
                                                   float* __restrict__ o)
{
    const int n = blockIdx.x;
    const int wid = threadIdx.x >> 6;     // 0..3
    const int lane = threadIdx.x & 63;
    const int j = lane & 31;              // neighbor slot
    const int half = lane >> 5;           // 0/1

    const int kidx = samp[n * KNEI + j];
    const float scale = 0.17677669529663687f;  // 1/sqrt(32)

    #pragma unroll
    for (int hh = 0; hh < 2; ++hh) {
        const int h = wid + hh * 4;       // heads 0..7 across 4 waves x 2 iters
        // ---- scores: lane (j, half) computes half the 32-dot ----
        const float* qrow = q + (size_t)n * DIM + h * HDIM + half * 16;
        const float* krow = k + (size_t)kidx * DIM + h * HDIM + half * 16;
        float part = 0.f;
        #pragma unroll
        for (int d = 0; d < 16; d += 4) {
            float4 qv = *(const float4*)(qrow + d);
            float4 kv = *(const float4*)(krow + d);
            part += qv.x * kv.x + qv.y * kv.y + qv.z * kv.z + qv.w * kv.w;
        }
        float score = (part + __shfl_xor(part, 32)) * scale;  // both halves hold score_j

        // ---- softmax over 32 neighbors (duplicated across halves) ----
        float m = score;
        #pragma unroll
        for (int sh = 16; sh; sh >>= 1) m = fmaxf(m, __shfl_xor(m, sh));
        float e = __expf(score - m);
        float sum = e;
        #pragma unroll
        for (int sh = 16; sh; sh >>= 1) sum += __shfl_xor(sum, sh);
        float p = e / sum;

        // ---- PV: lane (half, d) accumulates over 16 neighbors, combine halves ----
        const int d = lane & 31;
        float acc = 0.f;
        const float* vbase = v + h * HDIM + d;
        #pragma unroll
        for (int jj = 0; jj < 16; ++jj) {
            int js = half * 16 + jj;
            float pj = __shfl(p, js);
            int kj = __shfl(kidx, js);
            acc += pj * vbase[(size_t)kj * DIM];
        }
        acc += __shfl_xor(acc, 32);
        if (half == 0) o[(size_t)n * DIM + h * HDIM + d] = acc;
    }
}

// ---------------- fused residual add + LayerNorm ----------------
__global__ __launch_bounds__(256) void add_ln(const float* __restrict__ x,
                                              const float* __restrict__ y,
                                              const float* __restrict__ gamma,
                                              const float* __restrict__ beta,
                                              float* __restrict__ out, int M)
{
    const int row = blockIdx.x * 4 + (threadIdx.x >> 6);
    const int lane = threadIdx.x & 63;
    if (row >= M) return;

    const float4 xv = *(const float4*)(x + (size_t)row * DIM + lane * 4);
    const float4 yv = *(const float4*)(y + (size_t)row * DIM + lane * 4);
    float s0 = xv.x + yv.x, s1 = xv.y + yv.y, s2 = xv.z + yv.z, s3 = xv.w + yv.w;

    float sum = s0 + s1 + s2 + s3;
    float sq = s0 * s0 + s1 * s1 + s2 * s2 + s3 * s3;
    #pragma unroll
    for (int sh = 32; sh; sh >>= 1) {
        sum += __shfl_xor(sum, sh);
        sq  += __shfl_xor(sq, sh);
    }
    float mean = sum * (1.f / 256.f);
    float var = sq * (1.f / 256.f) - mean * mean;
    float rstd = rsqrtf(var + 1e-5f);

    const float4 gv = *(const float4*)(gamma + lane * 4);
    const float4 bv = *(const float4*)(beta + lane * 4);
    float4 ov;
    ov.x = (s0 - mean) * rstd * gv.x + bv.x;
    ov.y = (s1 - mean) * rstd * gv.y + bv.y;
    ov.z = (s2 - mean) * rstd * gv.z + bv.z;
    ov.w = (s3 - mean) * rstd * gv.w + bv.w;
    *(float4*)(out + (size_t)row * DIM + lane * 4) = ov;
}

extern "C" void kernel_launch(void* const* d_in, const int* in_sizes, int n_in,
                              void* d_out, int out_size, void* d_ws, size_t ws_size,
                              hipStream_t stream)
{
    const float* x    = (const float*)d_in[0];
    const int*   samp = (const int*)  d_in[1];
    const float* Wq = (const float*)d_in[2];  const float* bq = (const float*)d_in[3];
    const float* Wk = (const float*)d_in[4];  const float* bk = (const float*)d_in[5];
    const float* Wv = (const float*)d_in[6];  const float* bv = (const float*)d_in[7];
    const float* Wo = (const float*)d_in[8];  const float* bo = (const float*)d_in[9];
    const float* W1 = (const float*)d_in[10]; const float* b1 = (const float*)d_in[11];
    const float* W2 = (const float*)d_in[12]; const float* b2 = (const float*)d_in[13];
    const float* g1 = (const float*)d_in[14]; const float* be1 = (const float*)d_in[15];
    const float* g2 = (const float*)d_in[16]; const float* be2 = (const float*)d_in[17];
    float* out = (float*)d_out;

    const size_t ND = (size_t)NN * DIM;       // 5.12M floats
    float* ws   = (float*)d_ws;
    float* qb   = ws;                // [NN,DIM]   (later reused as attn_out)
    float* kb   = ws + ND;           // [NN,DIM]
    float* vb   = ws + 2 * ND;       // [NN,DIM]
    float* ob   = ws + 3 * ND;       // [NN,DIM]
    float* x1   = ws + 4 * ND;       // [NN,DIM]
    float* hmid = ws;                // [NN,DFFN] == 4*ND, reuses q/k/v/o region
    float* ff   = ws + 5 * ND;       // [NN,DIM]

    const dim3 blk(256);
    const dim3 g256(DIM / 64, (NN + 63) / 64);     // 4 x 313
    const dim3 g1024(DFFN / 64, (NN + 63) / 64);   // 16 x 313

    // QKV projections over all nodes (project-then-gather)
    gemm_bias<0><<<g256, blk, 0, stream>>>(x, Wq, bq, qb, NN, DIM, DIM);
    gemm_bias<0><<<g256, blk, 0, stream>>>(x, Wk, bk, kb, NN, DIM, DIM);
    gemm_bias<0><<<g256, blk, 0, stream>>>(x, Wv, bv, vb, NN, DIM, DIM);

    // per-node sampled-neighbor attention
    attn_kernel<<<NN, blk, 0, stream>>>(qb, kb, vb, samp, ob);

    // out proj (into qb, which is free) + residual + LN1
    gemm_bias<0><<<g256, blk, 0, stream>>>(ob, Wo, bo, qb, NN, DIM, DIM);
    add_ln<<<NN / 4, blk, 0, stream>>>(x, qb, g1, be1, x1, NN);

    // FFN
    gemm_bias<1><<<g1024, blk, 0, stream>>>(x1, W1, b1, hmid, NN, DFFN, DIM);
    gemm_bias<0><<<g256, blk, 0, stream>>>(hmid, W2, b2, ff, NN, DIM, DFFN);
    add_ln<<<NN / 4, blk, 0, stream>>>(x1, ff, g2, be2, out, NN);
}

// Round 2
// 233.668 us; speedup vs baseline: 3.0024x; 3.0024x over previous
//
#include <hip/hip_runtime.h>

#define NN 20000
#define KNEI 32
#define DIM 256
#define NHEAD 8
#define HDIM 32
#define DFFN 1024
#define QKVD 768

typedef __attribute__((ext_vector_type(8))) __bf16 bf16x8;
typedef __attribute__((ext_vector_type(8))) unsigned short u16x8;
typedef __attribute__((ext_vector_type(4))) unsigned short u16x4;
typedef __attribute__((ext_vector_type(4))) float f32x4;

static __device__ __forceinline__ float b2f(unsigned short u) {
    return __builtin_bit_cast(float, (unsigned)u << 16);
}
static __device__ __forceinline__ unsigned short f2b(float f) {
    unsigned u = __builtin_bit_cast(unsigned, f);
    return (unsigned short)((u + 0x7fff + ((u >> 16) & 1)) >> 16);
}

#define GLD16(src, dst)                                                          \
    __builtin_amdgcn_global_load_lds(                                            \
        (const __attribute__((address_space(1))) void*)(const void*)(src),       \
        (__attribute__((address_space(3))) void*)(void*)(dst), 16, 0, 0)

// ---------------- bf16 MFMA GEMM: C[M,N] = A[M,K] @ Bt[N,K]^T + bias ----------------
// m97 structure: 16B global_load_lds staging, [row][k] LDS tiles, 16x16x32 bf16 MFMA.
template<int BM, int RELU, int WF32, int WBF16>
__global__ __launch_bounds__(256) void gemm_mfma(const unsigned short* __restrict__ A,
                                                 const unsigned short* __restrict__ Bt,
                                                 const float* __restrict__ bias,
                                                 float* __restrict__ Cf,
                                                 unsigned short* __restrict__ Cb,
                                                 int M, int N, int K)
{
    constexpr int BN = 128, BK = 32;
    constexpr int MI = BM / 32;   // 16x16 frags per wave (rows); wave covers BM/2 x BN/2
    constexpr int NI = BN / 32;   // = 4

    __shared__ unsigned short As[BM * BK];  // [m][k] linear
    __shared__ unsigned short Bs[BN * BK];  // [n][k] linear

    const int tid  = threadIdx.x;
    const int wid  = tid >> 6;
    const int lane = tid & 63;
    const int bm = blockIdx.x * BM;
    const int bn = blockIdx.y * BN;
    const int wr = (wid >> 1) * (BM / 2);
    const int wc = (wid & 1) * (BN / 2);
    const int r0   = lane & 15;          // row/col within fragment
    const int kblk = (lane >> 4) * 8;    // k sub-block

    f32x4 acc[MI][NI];
    #pragma unroll
    for (int i = 0; i < MI; ++i)
        #pragma unroll
        for (int j = 0; j < NI; ++j)
            acc[i][j] = (f32x4){0.f, 0.f, 0.f, 0.f};

    for (int k0 = 0; k0 < K; k0 += BK) {
        // stage A tile: BM*4 16B chunks; chunk c = (row m = c>>2, k-off = (c&3)*8)
        constexpr int ACH = BM * 4;
        #pragma unroll
        for (int t = 0; t < ACH / 256; ++t) {
            int c = t * 256 + tid;
            int row = bm + (c >> 2);
            if (row >= M) row = M - 1;
            GLD16(A + (size_t)row * K + k0 + (c & 3) * 8,
                  &As[(t * 256 + wid * 64) * 8]);
        }
        // stage B tile: BN*4 chunks (N is always a multiple of BN)
        #pragma unroll
        for (int t = 0; t < (BN * 4) / 256; ++t) {
            int c = t * 256 + tid;
            GLD16(Bt + (size_t)(bn + (c >> 2)) * K + k0 + (c & 3) * 8,
                  &Bs[(t * 256 + wid * 64) * 8]);
        }
        __syncthreads();

        bf16x8 af[MI], bf[NI];
        #pragma unroll
        for (int mi = 0; mi < MI; ++mi)
            af[mi] = __builtin_bit_cast(bf16x8,
                     *(const u16x8*)&As[(wr + mi * 16 + r0) * BK + kblk]);
        #pragma unroll
        for (int ni = 0; ni < NI; ++ni)
            bf[ni] = __builtin_bit_cast(bf16x8,
                     *(const u16x8*)&Bs[(wc + ni * 16 + r0) * BK + kblk]);
        #pragma unroll
        for (int mi = 0; mi < MI; ++mi)
            #pragma unroll
            for (int ni = 0; ni < NI; ++ni)
                acc[mi][ni] = __builtin_amdgcn_mfma_f32_16x16x32_bf16(
                    af[mi], bf[ni], acc[mi][ni], 0, 0, 0);
        __syncthreads();
    }

    // epilogue: C/D mapping col=lane&15, row=(lane>>4)*4+reg
    const int r4 = (lane >> 4) * 4;
    #pragma unroll
    for (int mi = 0; mi < MI; ++mi)
        #pragma unroll
        for (int ni = 0; ni < NI; ++ni) {
            const int col = bn + wc + ni * 16 + r0;
            const float bb = bias[col];
            #pragma unroll
            for (int r = 0; r < 4; ++r) {
                const int row = bm + wr + mi * 16 + r4 + r;
                if (row < M) {
                    float v = acc[mi][ni][r] + bb;
                    if (RELU) v = fmaxf(v, 0.f);
                    if (WF32)  Cf[(size_t)row * N + col] = v;
                    if (WBF16) Cb[(size_t)row * N + col] = f2b(v);
                }
            }
        }
}

// ---------------- attention: per (node, head), bf16 in/out ----------------
__global__ __launch_bounds__(256) void attn_bf16(const unsigned short* __restrict__ qkv,
                                                 const int* __restrict__ samp,
                                                 unsigned short* __restrict__ o)
{
    const int n = blockIdx.x;
    const int wid = threadIdx.x >> 6;
    const int lane = threadIdx.x & 63;
    const int j = lane & 31;
    const int half = lane >> 5;

    const int kidx = samp[n * KNEI + j];
    const float scale = 0.17677669529663687f;  // 1/sqrt(32)

    #pragma unroll
    for (int hh = 0; hh < 2; ++hh) {
        const int h = wid + hh * 4;
        const unsigned short* qrow = qkv + (size_t)n * QKVD + h * HDIM + half * 16;
        const unsigned short* krow = qkv + (size_t)kidx * QKVD + 256 + h * HDIM + half * 16;
        u16x8 q0 = *(const u16x8*)qrow, q1 = *(const u16x8*)(qrow + 8);
        u16x8 kk0 = *(const u16x8*)krow, kk1 = *(const u16x8*)(krow + 8);
        float part = 0.f;
        #pragma unroll
        for (int d = 0; d < 8; ++d)
            part += b2f(q0[d]) * b2f(kk0[d]) + b2f(q1[d]) * b2f(kk1[d]);
        float score = (part + __shfl_xor(part, 32)) * scale;

        float m = score;
        #pragma unroll
        for (int sh = 16; sh; sh >>= 1) m = fmaxf(m, __shfl_xor(m, sh));
        float e = __expf(score - m);
        float sum = e;
        #pragma unroll
        for (int sh = 16; sh; sh >>= 1) sum += __shfl_xor(sum, sh);
        float p = e / sum;

        const int d = lane & 31;
        float acc = 0.f;
        const unsigned short* vbase = qkv + 512 + h * HDIM + d;
        #pragma unroll
        for (int jj = 0; jj < 16; ++jj) {
            int js = half * 16 + jj;
            float pj = __shfl(p, js);
            int kj = __shfl(kidx, js);
            acc += pj * b2f(vbase[(size_t)kj * QKVD]);
        }
        acc += __shfl_xor(acc, 32);
        if (half == 0) o[(size_t)n * DIM + h * HDIM + d] = f2b(acc);
    }
}

// ---------------- fused residual add + LayerNorm (fp32 out + optional bf16 out) ----------------
template<int WB>
__global__ __launch_bounds__(256) void add_ln(const float* __restrict__ x,
                                              const float* __restrict__ y,
                                              const float* __restrict__ gamma,
                                              const float* __restrict__ beta,
                                              float* __restrict__ outf,
                                              unsigned short* __restrict__ outb, int M)
{
    const int row = blockIdx.x * 4 + (threadIdx.x >> 6);
    const int lane = threadIdx.x & 63;
    if (row >= M) return;

    const float4 xv = *(const float4*)(x + (size_t)row * DIM + lane * 4);
    const float4 yv = *(const float4*)(y + (size_t)row * DIM + lane * 4);
    float s0 = xv.x + yv.x, s1 = xv.y + yv.y, s2 = xv.z + yv.z, s3 = xv.w + yv.w;

    float sum = s0 + s1 + s2 + s3;
    float sq = s0 * s0 + s1 * s1 + s2 * s2 + s3 * s3;
    #pragma unroll
    for (int sh = 32; sh; sh >>= 1) {
        sum += __shfl_xor(sum, sh);
        sq  += __shfl_xor(sq, sh);
    }
    float mean = sum * (1.f / 256.f);
    float var = sq * (1.f / 256.f) - mean * mean;
    float rstd = rsqrtf(var + 1e-5f);

    const float4 gv = *(const float4*)(gamma + lane * 4);
    const float4 bv = *(const float4*)(beta + lane * 4);
    float4 ov;
    ov.x = (s0 - mean) * rstd * gv.x + bv.x;
    ov.y = (s1 - mean) * rstd * gv.y + bv.y;
    ov.z = (s2 - mean) * rstd * gv.z + bv.z;
    ov.w = (s3 - mean) * rstd * gv.w + bv.w;
    *(float4*)(outf + (size_t)row * DIM + lane * 4) = ov;
    if (WB) {
        u16x4 bb = { f2b(ov.x), f2b(ov.y), f2b(ov.z), f2b(ov.w) };
        *(u16x4*)(outb + (size_t)row * DIM + lane * 4) = bb;
    }
}

// ---------------- conversions ----------------
__global__ __launch_bounds__(256) void cvt_bf16(const float* __restrict__ in,
                                                unsigned short* __restrict__ out, int n4)
{
    int i = blockIdx.x * 256 + threadIdx.x;
    if (i < n4) {
        float4 v = ((const float4*)in)[i];
        u16x4 b = { f2b(v.x), f2b(v.y), f2b(v.z), f2b(v.w) };
        ((u16x4*)out)[i] = b;
    }
}

// W [K][N] fp32 -> Wt [N][K] bf16 (32x32 LDS tile transpose)
__global__ __launch_bounds__(256) void cvt_transpose(const float* __restrict__ W,
                                                     unsigned short* __restrict__ Wt,
                                                     int K, int N)
{
    __shared__ float t[32][33];
    const int n0 = blockIdx.x * 32, k0 = blockIdx.y * 32;
    const int tx = threadIdx.x & 31, ty = threadIdx.x >> 5;
    #pragma unroll
    for (int i = 0; i < 32; i += 8)
        t[ty + i][tx] = W[(size_t)(k0 + ty + i) * N + n0 + tx];
    __syncthreads();
    #pragma unroll
    for (int i = 0; i < 32; i += 8)
        Wt[(size_t)(n0 + ty + i) * K + k0 + tx] = f2b(t[tx][ty + i]);
}

__global__ void concat_bias(const float* a, const float* b, const float* c, float* out)
{
    int i = blockIdx.x * 256 + threadIdx.x;
    if (i < 256) out[i] = a[i];
    else if (i < 512) out[i] = b[i - 256];
    else if (i < 768) out[i] = c[i - 512];
}

extern "C" void kernel_launch(void* const* d_in, const int* in_sizes, int n_in,
                              void* d_out, int out_size, void* d_ws, size_t ws_size,
                              hipStream_t stream)
{
    const float* x    = (const float*)d_in[0];
    const int*   samp = (const int*)  d_in[1];
    const float* Wq = (const float*)d_in[2];  const float* bq = (const float*)d_in[3];
    const float* Wk = (const float*)d_in[4];  const float* bk = (const float*)d_in[5];
    const float* Wv = (const float*)d_in[6];  const float* bv = (const float*)d_in[7];
    const float* Wo = (const float*)d_in[8];  const float* bo = (const float*)d_in[9];
    const float* W1 = (const float*)d_in[10]; const float* b1 = (const float*)d_in[11];
    const float* W2 = (const float*)d_in[12]; const float* b2 = (const float*)d_in[13];
    const float* g1 = (const float*)d_in[14]; const float* be1 = (const float*)d_in[15];
    const float* g2 = (const float*)d_in[16]; const float* be2 = (const float*)d_in[17];
    float* out = (float*)d_out;

    char* w = (char*)d_ws;
    // weights (live whole launch)
    unsigned short* WqkvT = (unsigned short*)(w + 0);          // [768][256]
    unsigned short* WoT   = (unsigned short*)(w + 393216);     // [256][256]
    unsigned short* W1T   = (unsigned short*)(w + 524288);     // [1024][256]
    unsigned short* W2T   = (unsigned short*)(w + 1048576);    // [256][1024]
    float*          bqkv  = (float*)(w + 1572864);             // [768]
    // activations (regions reused over the timeline; see liveness notes)
    unsigned short* xb    = (unsigned short*)(w + (2u << 20));   // [NN][256] bf16; dead after QKV
    unsigned short* qkvb  = (unsigned short*)(w + (16u << 20));  // [NN][768] bf16; dead after attn
    unsigned short* ob    = xb;                                  // [NN][256] bf16 (reuse xb)
    float*          attno = (float*)(w + (48u << 20));           // [NN][256] f32; dead after LN1
    float*          x1    = (float*)(w + (72u << 20));           // [NN][256] f32; live to LN2
    unsigned short* x1b   = (unsigned short*)(w + (16u << 20));  // reuse qkvb region
    unsigned short* hmid  = (unsigned short*)(w + (28u << 20));  // [NN][1024] bf16 (over dead qkvb tail+attno)
    float*          ff    = (float*)(w + (96u << 20));           // [NN][256] f32

    const dim3 blk(256);

    // ---- weight prep (1.6 MB total, ~negligible) ----
    cvt_transpose<<<dim3(8, 8),  blk, 0, stream>>>(Wq, WqkvT,             DIM, DIM);
    cvt_transpose<<<dim3(8, 8),  blk, 0, stream>>>(Wk, WqkvT + 256 * 256, DIM, DIM);
    cvt_transpose<<<dim3(8, 8),  blk, 0, stream>>>(Wv, WqkvT + 512 * 256, DIM, DIM);
    cvt_transpose<<<dim3(8, 8),  blk, 0, stream>>>(Wo, WoT,               DIM, DIM);
    cvt_transpose<<<dim3(32, 8), blk, 0, stream>>>(W1, W1T,               DIM, DFFN);
    cvt_transpose<<<dim3(8, 32), blk, 0, stream>>>(W2, W2T,               DFFN, DIM);
    concat_bias<<<dim3(3), blk, 0, stream>>>(bq, bk, bv, bqkv);
    cvt_bf16<<<dim3((NN * DIM / 4 + 255) / 256), blk, 0, stream>>>(x, xb, NN * DIM / 4);

    // ---- QKV fused projection: [NN,256] @ [256,768] -> bf16 [NN,768] ----
    gemm_mfma<128, 0, 0, 1><<<dim3(157, 6), blk, 0, stream>>>(
        xb, WqkvT, bqkv, nullptr, qkvb, NN, QKVD, DIM);

    // ---- attention ----
    attn_bf16<<<dim3(NN), blk, 0, stream>>>(qkvb, samp, ob);

    // ---- out proj -> fp32, then residual+LN1 (emit bf16 too) ----
    gemm_mfma<64, 0, 1, 0><<<dim3(313, 2), blk, 0, stream>>>(
        ob, WoT, bo, attno, nullptr, NN, DIM, DIM);
    add_ln<1><<<dim3(NN / 4), blk, 0, stream>>>(x, attno, g1, be1, x1, x1b, NN);

    // ---- FFN ----
    gemm_mfma<128, 1, 0, 1><<<dim3(157, 8), blk, 0, stream>>>(
        x1b, W1T, b1, nullptr, hmid, NN, DFFN, DIM);
    gemm_mfma<64, 0, 1, 0><<<dim3(313, 2), blk, 0, stream>>>(
        hmid, W2T, b2, ff, nullptr, NN, DIM, DFFN);
    add_ln<0><<<dim3(NN / 4), blk, 0, stream>>>(x1, ff, g2, be2, out, nullptr, NN);
}

// Round 6
// 221.836 us; speedup vs baseline: 3.1625x; 1.0533x over previous
//
#include <hip/hip_runtime.h>

#define NN 20000
#define KNEI 32
#define DIM 256
#define NHEAD 8
#define HDIM 32
#define DFFN 1024
#define QKVD 768

typedef __attribute__((ext_vector_type(8))) __bf16 bf16x8;
typedef __attribute__((ext_vector_type(8))) unsigned short u16x8;
typedef __attribute__((ext_vector_type(4))) unsigned short u16x4;
typedef __attribute__((ext_vector_type(4))) float f32x4;

static __device__ __forceinline__ float b2f(unsigned short u) {
    return __builtin_bit_cast(float, (unsigned)u << 16);
}
static __device__ __forceinline__ unsigned short f2b(float f) {
    unsigned u = __builtin_bit_cast(unsigned, f);
    return (unsigned short)((u + 0x7fff + ((u >> 16) & 1)) >> 16);
}

// ---- fp8 e4m3fn encode/decode (HW builtins on device; pure-bit-ops fallback
// so the HOST compile pass can always parse this file) ----
static __device__ __forceinline__ unsigned char fp8enc(float v) {
#if defined(__HIP_DEVICE_COMPILE__) && __has_builtin(__builtin_amdgcn_cvt_pk_fp8_f32)
    return (unsigned char)(__builtin_amdgcn_cvt_pk_fp8_f32(v, v, 0u, false) & 0xffu);
#else
    unsigned u = __builtin_bit_cast(unsigned, v);
    unsigned s = u >> 31;
    unsigned a = u & 0x7fffffffu;
    if (a >= 0x43e00000u) return (unsigned char)((s << 7) | 0x7e);  // clamp to 448
    float af = __builtin_bit_cast(float, a);
    if (af < 0.015625f) {                       // subnormal: step 2^-9
        unsigned r = (unsigned)(af * 512.0f + 0.5f);
        if (r >= 8u) return (unsigned char)((s << 7) | 0x08);
        return (unsigned char)((s << 7) | r);
    }
    unsigned lsb = (a >> 20) & 1u;              // RNE to 3 mantissa bits
    a += 0x7ffffu + lsb;
    unsigned e = (a >> 23) - 120u;
    unsigned m = (a >> 20) & 7u;
    unsigned code = (e << 3) | m;
    if (code > 0x7eu) code = 0x7eu;
    return (unsigned char)((s << 7) | code);
#endif
}

template<int SEL>
static __device__ __forceinline__ float fp8dec(unsigned word) {
#if defined(__HIP_DEVICE_COMPILE__) && __has_builtin(__builtin_amdgcn_cvt_f32_fp8)
    return __builtin_amdgcn_cvt_f32_fp8(word, SEL);
#else
    unsigned b = (word >> (SEL * 8)) & 0xffu;
    unsigned s = (b >> 7) & 1u;
    unsigned e = (b >> 3) & 0xfu;
    unsigned m = b & 7u;
    float v;
    if (e == 0) v = (float)m * 0.001953125f;    // m * 2^-9
    else        v = __builtin_bit_cast(float, ((e + 120u) << 23) | (m << 20));
    return s ? -v : v;
#endif
}

#define GLD16(src, dst)                                                          \
    __builtin_amdgcn_global_load_lds(                                            \
        (const __attribute__((address_space(1))) void*)(const void*)(src),       \
        (__attribute__((address_space(3))) void*)(void*)(dst), 16, 0, 0)

// ---------------- bf16 MFMA GEMM: C[M,N] = A[M,K] @ Bt[N,K]^T + bias ----------------
// SPLIT: Q cols (<256) -> bf16 Cb, K/V cols -> fp8 kvb rows [k(256)|v(256)]
template<int BM, int RELU, int WF32, int WBF16, int SPLIT>
__global__ __launch_bounds__(256) void gemm_mfma(const unsigned short* __restrict__ A,
                                                 const unsigned short* __restrict__ Bt,
                                                 const float* __restrict__ bias,
                                                 float* __restrict__ Cf,
                                                 unsigned short* __restrict__ Cb,
                                                 unsigned char* __restrict__ kvb,
                                                 int M, int N, int K)
{
    constexpr int BN = 128, BK = 32;
    constexpr int MI = BM / 32;
    constexpr int NI = BN / 32;

    __shared__ unsigned short As[BM * BK];
    __shared__ unsigned short Bs[BN * BK];

    const int tid  = threadIdx.x;
    const int wid  = tid >> 6;
    const int lane = tid & 63;
    const int bm = blockIdx.x * BM;
    const int bn = blockIdx.y * BN;
    const int wr = (wid >> 1) * (BM / 2);
    const int wc = (wid & 1) * (BN / 2);
    const int r0   = lane & 15;
    const int kblk = (lane >> 4) * 8;

    f32x4 acc[MI][NI];
    #pragma unroll
    for (int i = 0; i < MI; ++i)
        #pragma unroll
        for (int j = 0; j < NI; ++j)
            acc[i][j] = (f32x4){0.f, 0.f, 0.f, 0.f};

    for (int k0 = 0; k0 < K; k0 += BK) {
        constexpr int ACH = BM * 4;
        #pragma unroll
        for (int t = 0; t < ACH / 256; ++t) {
            int c = t * 256 + tid;
            int row = bm + (c >> 2);
            if (row >= M) row = M - 1;
            GLD16(A + (size_t)row * K + k0 + (c & 3) * 8,
                  &As[(t * 256 + wid * 64) * 8]);
        }
        #pragma unroll
        for (int t = 0; t < (BN * 4) / 256; ++t) {
            int c = t * 256 + tid;
            GLD16(Bt + (size_t)(bn + (c >> 2)) * K + k0 + (c & 3) * 8,
                  &Bs[(t * 256 + wid * 64) * 8]);
        }
        __syncthreads();

        bf16x8 af[MI], bfr[NI];
        #pragma unroll
        for (int mi = 0; mi < MI; ++mi)
            af[mi] = __builtin_bit_cast(bf16x8,
                     *(const u16x8*)&As[(wr + mi * 16 + r0) * BK + kblk]);
        #pragma unroll
        for (int ni = 0; ni < NI; ++ni)
            bfr[ni] = __builtin_bit_cast(bf16x8,
                     *(const u16x8*)&Bs[(wc + ni * 16 + r0) * BK + kblk]);
        #pragma unroll
        for (int mi = 0; mi < MI; ++mi)
            #pragma unroll
            for (int ni = 0; ni < NI; ++ni)
                acc[mi][ni] = __builtin_amdgcn_mfma_f32_16x16x32_bf16(
                    af[mi], bfr[ni], acc[mi][ni], 0, 0, 0);
        __syncthreads();
    }

    const int r4 = (lane >> 4) * 4;
    #pragma unroll
    for (int mi = 0; mi < MI; ++mi)
        #pragma unroll
        for (int ni = 0; ni < NI; ++ni) {
            const int col = bn + wc + ni * 16 + r0;
            const float bb = bias[col];
            #pragma unroll
            for (int r = 0; r < 4; ++r) {
                const int row = bm + wr + mi * 16 + r4 + r;
                if (row < M) {
                    float v = acc[mi][ni][r] + bb;
                    if (RELU) v = fmaxf(v, 0.f);
                    if (SPLIT) {
                        if (col < 256) Cb[(size_t)row * DIM + col] = f2b(v);
                        else kvb[(size_t)row * 512 + (col - 256)] = fp8enc(v);
                    } else {
                        if (WF32)  Cf[(size_t)row * N + col] = v;
                        if (WBF16) Cb[(size_t)row * N + col] = f2b(v);
                    }
                }
            }
        }
}

// ---------------- attention: per (node, head), q bf16, k/v fp8 ----------------
__global__ __launch_bounds__(256) void attn_f8(const unsigned short* __restrict__ q,
                                               const unsigned char* __restrict__ kv,
                                               const int* __restrict__ samp,
                                               unsigned short* __restrict__ o)
{
    const int n = blockIdx.x;
    const int wid = threadIdx.x >> 6;
    const int lane = threadIdx.x & 63;
    const int j = lane & 31;
    const int half = lane >> 5;

    const int kidx = samp[n * KNEI + j];
    const float scale = 0.17677669529663687f;  // 1/sqrt(32)

    #pragma unroll
    for (int hh = 0; hh < 2; ++hh) {
        const int h = wid + hh * 4;
        // ---- score: lane (j, half) does 16 of the 32 dims ----
        const unsigned short* qrow = q + (size_t)n * DIM + h * HDIM + half * 16;
        u16x8 q0 = *(const u16x8*)qrow, q1 = *(const u16x8*)(qrow + 8);
        uint4 kw = *(const uint4*)(kv + (size_t)kidx * 512 + h * HDIM + half * 16);
        float kf[16];
        kf[0]  = fp8dec<0>(kw.x); kf[1]  = fp8dec<1>(kw.x);
        kf[2]  = fp8dec<2>(kw.x); kf[3]  = fp8dec<3>(kw.x);
        kf[4]  = fp8dec<0>(kw.y); kf[5]  = fp8dec<1>(kw.y);
        kf[6]  = fp8dec<2>(kw.y); kf[7]  = fp8dec<3>(kw.y);
        kf[8]  = fp8dec<0>(kw.z); kf[9]  = fp8dec<1>(kw.z);
        kf[10] = fp8dec<2>(kw.z); kf[11] = fp8dec<3>(kw.z);
        kf[12] = fp8dec<0>(kw.w); kf[13] = fp8dec<1>(kw.w);
        kf[14] = fp8dec<2>(kw.w); kf[15] = fp8dec<3>(kw.w);
        float part = 0.f;
        #pragma unroll
        for (int d = 0; d < 8; ++d)
            part += b2f(q0[d]) * kf[d] + b2f(q1[d]) * kf[d + 8];
        float score = (part + __shfl_xor(part, 32)) * scale;

        // ---- softmax over 32 neighbors ----
        float m = score;
        #pragma unroll
        for (int sh = 16; sh; sh >>= 1) m = fmaxf(m, __shfl_xor(m, sh));
        float e = __expf(score - m);
        float sum = e;
        #pragma unroll
        for (int sh = 16; sh; sh >>= 1) sum += __shfl_xor(sum, sh);
        float p = e / sum;

        // ---- PV: lane (half, d) over 16 neighbors ----
        const int d = lane & 31;
        float acc = 0.f;
        const unsigned char* vbase = kv + 256 + h * HDIM + d;
        #pragma unroll
        for (int jj = 0; jj < 16; ++jj) {
            int js = half * 16 + jj;
            float pj = __shfl(p, js);
            int kj = __shfl(kidx, js);
            unsigned vb = vbase[(size_t)kj * 512];
            acc += pj * fp8dec<0>(vb);
        }
        acc += __shfl_xor(acc, 32);
        if (half == 0) o[(size_t)n * DIM + h * HDIM + d] = f2b(acc);
    }
}

// ---------------- fused residual add + LayerNorm ----------------
// XF32: residual input fp32 (else bf16). WFOUT: write fp32 out (else bf16 out).
template<int XF32, int WFOUT>
__global__ __launch_bounds__(256) void add_ln(const float* __restrict__ xf,
                                              const unsigned short* __restrict__ xb,
                                              const unsigned short* __restrict__ y,
                                              const float* __restrict__ gamma,
                                              const float* __restrict__ beta,
                                              float* __restrict__ outf,
                                              unsigned short* __restrict__ outb, int M)
{
    const int row = blockIdx.x * 4 + (threadIdx.x >> 6);
    const int lane = threadIdx.x & 63;
    if (row >= M) return;

    float s0, s1, s2, s3;
    if (XF32) {
        const float4 xv = *(const float4*)(xf + (size_t)row * DIM + lane * 4);
        s0 = xv.x; s1 = xv.y; s2 = xv.z; s3 = xv.w;
    } else {
        const u16x4 xv = *(const u16x4*)(xb + (size_t)row * DIM + lane * 4);
        s0 = b2f(xv[0]); s1 = b2f(xv[1]); s2 = b2f(xv[2]); s3 = b2f(xv[3]);
    }
    const u16x4 yv = *(const u16x4*)(y + (size_t)row * DIM + lane * 4);
    s0 += b2f(yv[0]); s1 += b2f(yv[1]); s2 += b2f(yv[2]); s3 += b2f(yv[3]);

    float sum = s0 + s1 + s2 + s3;
    float sq = s0 * s0 + s1 * s1 + s2 * s2 + s3 * s3;
    #pragma unroll
    for (int sh = 32; sh; sh >>= 1) {
        sum += __shfl_xor(sum, sh);
        sq  += __shfl_xor(sq, sh);
    }
    float mean = sum * (1.f / 256.f);
    float var = sq * (1.f / 256.f) - mean * mean;
    float rstd = rsqrtf(var + 1e-5f);

    const float4 gv = *(const float4*)(gamma + lane * 4);
    const float4 bv = *(const float4*)(beta + lane * 4);
    float o0 = (s0 - mean) * rstd * gv.x + bv.x;
    float o1 = (s1 - mean) * rstd * gv.y + bv.y;
    float o2 = (s2 - mean) * rstd * gv.z + bv.z;
    float o3 = (s3 - mean) * rstd * gv.w + bv.w;
    if (WFOUT) {
        float4 ov = { o0, o1, o2, o3 };
        *(float4*)(outf + (size_t)row * DIM + lane * 4) = ov;
    } else {
        u16x4 bb = { f2b(o0), f2b(o1), f2b(o2), f2b(o3) };
        *(u16x4*)(outb + (size_t)row * DIM + lane * 4) = bb;
    }
}

// ---------------- conversions ----------------
__global__ __launch_bounds__(256) void cvt_bf16(const float* __restrict__ in,
                                                unsigned short* __restrict__ out, int n4)
{
    int i = blockIdx.x * 256 + threadIdx.x;
    if (i < n4) {
        float4 v = ((const float4*)in)[i];
        u16x4 b = { f2b(v.x), f2b(v.y), f2b(v.z), f2b(v.w) };
        ((u16x4*)out)[i] = b;
    }
}

__global__ __launch_bounds__(256) void cvt_transpose(const float* __restrict__ W,
                                                     unsigned short* __restrict__ Wt,
                                                     int K, int N)
{
    __shared__ float t[32][33];
    const int n0 = blockIdx.x * 32, k0 = blockIdx.y * 32;
    const int tx = threadIdx.x & 31, ty = threadIdx.x >> 5;
    #pragma unroll
    for (int i = 0; i < 32; i += 8)
        t[ty + i][tx] = W[(size_t)(k0 + ty + i) * N + n0 + tx];
    __syncthreads();
    #pragma unroll
    for (int i = 0; i < 32; i += 8)
        Wt[(size_t)(n0 + ty + i) * K + k0 + tx] = f2b(t[tx][ty + i]);
}

__global__ void concat_bias(const float* a, const float* b, const float* c, float* out)
{
    int i = blockIdx.x * 256 + threadIdx.x;
    if (i < 256) out[i] = a[i];
    else if (i < 512) out[i] = b[i - 256];
    else if (i < 768) out[i] = c[i - 512];
}

extern "C" void kernel_launch(void* const* d_in, const int* in_sizes, int n_in,
                              void* d_out, int out_size, void* d_ws, size_t ws_size,
                              hipStream_t stream)
{
    const float* x    = (const float*)d_in[0];
    const int*   samp = (const int*)  d_in[1];
    const float* Wq = (const float*)d_in[2];  const float* bq = (const float*)d_in[3];
    const float* Wk = (const float*)d_in[4];  const float* bk = (const float*)d_in[5];
    const float* Wv = (const float*)d_in[6];  const float* bv = (const float*)d_in[7];
    const float* Wo = (const float*)d_in[8];  const float* bo = (const float*)d_in[9];
    const float* W1 = (const float*)d_in[10]; const float* b1 = (const float*)d_in[11];
    const float* W2 = (const float*)d_in[12]; const float* b2 = (const float*)d_in[13];
    const float* g1 = (const float*)d_in[14]; const float* be1 = (const float*)d_in[15];
    const float* g2 = (const float*)d_in[16]; const float* be2 = (const float*)d_in[17];
    float* out = (float*)d_out;

    char* w = (char*)d_ws;
    const size_t MB = 1u << 20;
    // weights (live whole launch): 0 .. 2 MB
    unsigned short* WqkvT = (unsigned short*)(w + 0);          // [768][256] bf16
    unsigned short* WoT   = (unsigned short*)(w + 393216);     // [256][256]
    unsigned short* W1T   = (unsigned short*)(w + 524288);     // [1024][256]
    unsigned short* W2T   = (unsigned short*)(w + 1048576);    // [256][1024]
    float*          bqkv  = (float*)(w + 1572864);             // [768]
    // activations — NON-OVERLAPPING liveness map (round-5 bug: hmid over x1b):
    //   xb/ob  2..12.24MB | qb 13..23.24 | kvb 24..34.24 | attno 35..45.24
    //   x1b   46..56.24   | hmid 57..97.96
    unsigned short* xb    = (unsigned short*)(w + 2 * MB);     // [NN][256] bf16
    unsigned short* qb    = (unsigned short*)(w + 13 * MB);    // [NN][256] bf16
    unsigned char*  kvb   = (unsigned char*) (w + 24 * MB);    // [NN][512] fp8
    unsigned short* ob    = xb;                                // reuse xb (dead after QKV)
    unsigned short* attno = (unsigned short*)(w + 35 * MB);    // [NN][256] bf16
    unsigned short* x1b   = (unsigned short*)(w + 46 * MB);    // [NN][256] bf16; live to LN2
    unsigned short* hmid  = (unsigned short*)(w + 57 * MB);    // [NN][1024] bf16
    unsigned short* ffb   = attno;                             // reuse attno (dead after LN1)

    const dim3 blk(256);

    // ---- weight prep ----
    cvt_transpose<<<dim3(8, 8),  blk, 0, stream>>>(Wq, WqkvT,             DIM, DIM);
    cvt_transpose<<<dim3(8, 8),  blk, 0, stream>>>(Wk, WqkvT + 256 * 256, DIM, DIM);
    cvt_transpose<<<dim3(8, 8),  blk, 0, stream>>>(Wv, WqkvT + 512 * 256, DIM, DIM);
    cvt_transpose<<<dim3(8, 8),  blk, 0, stream>>>(Wo, WoT,               DIM, DIM);
    cvt_transpose<<<dim3(32, 8), blk, 0, stream>>>(W1, W1T,               DIM, DFFN);
    cvt_transpose<<<dim3(8, 32), blk, 0, stream>>>(W2, W2T,               DFFN, DIM);
    concat_bias<<<dim3(3), blk, 0, stream>>>(bq, bk, bv, bqkv);
    cvt_bf16<<<dim3((NN * DIM / 4 + 255) / 256), blk, 0, stream>>>(x, xb, NN * DIM / 4);

    // ---- fused QKV projection: Q->bf16, K/V->fp8 ----
    gemm_mfma<128, 0, 0, 0, 1><<<dim3(157, 6), blk, 0, stream>>>(
        xb, WqkvT, bqkv, nullptr, qb, kvb, NN, QKVD, DIM);

    // ---- attention ----
    attn_f8<<<dim3(NN), blk, 0, stream>>>(qb, kvb, samp, ob);

    // ---- out proj -> bf16, residual(x f32)+LN1 -> bf16 ----
    gemm_mfma<64, 0, 0, 1, 0><<<dim3(313, 2), blk, 0, stream>>>(
        ob, WoT, bo, nullptr, attno, nullptr, NN, DIM, DIM);
    add_ln<1, 0><<<dim3(NN / 4), blk, 0, stream>>>(x, nullptr, attno, g1, be1,
                                                   nullptr, x1b, NN);

    // ---- FFN ----
    gemm_mfma<128, 1, 0, 1, 0><<<dim3(157, 8), blk, 0, stream>>>(
        x1b, W1T, b1, nullptr, hmid, nullptr, NN, DFFN, DIM);
    gemm_mfma<64, 0, 0, 1, 0><<<dim3(313, 2), blk, 0, stream>>>(
        hmid, W2T, b2, nullptr, ffb, nullptr, NN, DIM, DFFN);
    add_ln<0, 1><<<dim3(NN / 4), blk, 0, stream>>>(nullptr, x1b, ffb, g2, be2,
                                                   out, nullptr, NN);
}

// Round 7
// 188.879 us; speedup vs baseline: 3.7143x; 1.1745x over previous
//
#include <hip/hip_runtime.h>

#define NN 20000
#define KNEI 32
#define DIM 256
#define NHEAD 8
#define HDIM 32
#define DFFN 1024
#define QKVD 768

typedef __attribute__((ext_vector_type(8))) __bf16 bf16x8;
typedef __attribute__((ext_vector_type(8))) unsigned short u16x8;
typedef __attribute__((ext_vector_type(4))) unsigned short u16x4;
typedef __attribute__((ext_vector_type(4))) float f32x4;
typedef __attribute__((ext_vector_type(2))) float f32x2;

static __device__ __forceinline__ float b2f(unsigned short u) {
    return __builtin_bit_cast(float, (unsigned)u << 16);
}
static __device__ __forceinline__ float blo(unsigned w) {   // low bf16 of packed pair
    return __builtin_bit_cast(float, w << 16);
}
static __device__ __forceinline__ float bhi(unsigned w) {   // high bf16 of packed pair
    return __builtin_bit_cast(float, w & 0xffff0000u);
}
static __device__ __forceinline__ unsigned short f2b(float f) {
    unsigned u = __builtin_bit_cast(unsigned, f);
    return (unsigned short)((u + 0x7fff + ((u >> 16) & 1)) >> 16);
}

// ---- fp8 e4m3fn encode/decode (HW builtins on device; pure-bit-ops fallback
// so the HOST compile pass can always parse this file) ----
static __device__ __forceinline__ unsigned char fp8enc(float v) {
#if defined(__HIP_DEVICE_COMPILE__) && __has_builtin(__builtin_amdgcn_cvt_pk_fp8_f32)
    return (unsigned char)(__builtin_amdgcn_cvt_pk_fp8_f32(v, v, 0u, false) & 0xffu);
#else
    unsigned u = __builtin_bit_cast(unsigned, v);
    unsigned s = u >> 31;
    unsigned a = u & 0x7fffffffu;
    if (a >= 0x43e00000u) return (unsigned char)((s << 7) | 0x7e);  // clamp to 448
    float af = __builtin_bit_cast(float, a);
    if (af < 0.015625f) {                       // subnormal: step 2^-9
        unsigned r = (unsigned)(af * 512.0f + 0.5f);
        if (r >= 8u) return (unsigned char)((s << 7) | 0x08);
        return (unsigned char)((s << 7) | r);
    }
    unsigned lsb = (a >> 20) & 1u;              // RNE to 3 mantissa bits
    a += 0x7ffffu + lsb;
    unsigned e = (a >> 23) - 120u;
    unsigned m = (a >> 20) & 7u;
    unsigned code = (e << 3) | m;
    if (code > 0x7eu) code = 0x7eu;
    return (unsigned char)((s << 7) | code);
#endif
}

template<int SEL>
static __device__ __forceinline__ float fp8dec(unsigned word) {
#if defined(__HIP_DEVICE_COMPILE__) && __has_builtin(__builtin_amdgcn_cvt_f32_fp8)
    return __builtin_amdgcn_cvt_f32_fp8(word, SEL);
#else
    unsigned b = (word >> (SEL * 8)) & 0xffu;
    unsigned s = (b >> 7) & 1u;
    unsigned e = (b >> 3) & 0xfu;
    unsigned m = b & 7u;
    float v;
    if (e == 0) v = (float)m * 0.001953125f;    // m * 2^-9
    else        v = __builtin_bit_cast(float, ((e + 120u) << 23) | (m << 20));
    return s ? -v : v;
#endif
}

// paired fp8 decode: bytes (0,1) for HI=false, (2,3) for HI=true
template<bool HI>
static __device__ __forceinline__ f32x2 fp8pk(unsigned word) {
#if defined(__HIP_DEVICE_COMPILE__) && __has_builtin(__builtin_amdgcn_cvt_pk_f32_fp8)
    return __builtin_amdgcn_cvt_pk_f32_fp8((int)word, HI);
#else
    f32x2 r;
    r.x = fp8dec<HI ? 2 : 0>(word);
    r.y = fp8dec<HI ? 3 : 1>(word);
    return r;
#endif
}

#define GLD16(src, dst)                                                          \
    __builtin_amdgcn_global_load_lds(                                            \
        (const __attribute__((address_space(1))) void*)(const void*)(src),       \
        (__attribute__((address_space(3))) void*)(void*)(dst), 16, 0, 0)

// ---------------- bf16 MFMA GEMM: C[M,N] = A[M,K] @ Bt[N,K]^T + bias ----------------
// SPLIT: Q cols (<256) -> bf16 Cb, K/V cols -> fp8 kvb rows [k(256)|v(256)]
template<int BM, int RELU, int WF32, int WBF16, int SPLIT>
__global__ __launch_bounds__(256) void gemm_mfma(const unsigned short* __restrict__ A,
                                                 const unsigned short* __restrict__ Bt,
                                                 const float* __restrict__ bias,
                                                 float* __restrict__ Cf,
                                                 unsigned short* __restrict__ Cb,
                                                 unsigned char* __restrict__ kvb,
                                                 int M, int N, int K)
{
    constexpr int BN = 128, BK = 32;
    constexpr int MI = BM / 32;
    constexpr int NI = BN / 32;

    __shared__ unsigned short As[BM * BK];
    __shared__ unsigned short Bs[BN * BK];

    const int tid  = threadIdx.x;
    const int wid  = tid >> 6;
    const int lane = tid & 63;
    const int bm = blockIdx.x * BM;
    const int bn = blockIdx.y * BN;
    const int wr = (wid >> 1) * (BM / 2);
    const int wc = (wid & 1) * (BN / 2);
    const int r0   = lane & 15;
    const int kblk = (lane >> 4) * 8;

    f32x4 acc[MI][NI];
    #pragma unroll
    for (int i = 0; i < MI; ++i)
        #pragma unroll
        for (int j = 0; j < NI; ++j)
            acc[i][j] = (f32x4){0.f, 0.f, 0.f, 0.f};

    for (int k0 = 0; k0 < K; k0 += BK) {
        constexpr int ACH = BM * 4;
        #pragma unroll
        for (int t = 0; t < ACH / 256; ++t) {
            int c = t * 256 + tid;
            int row = bm + (c >> 2);
            if (row >= M) row = M - 1;
            GLD16(A + (size_t)row * K + k0 + (c & 3) * 8,
                  &As[(t * 256 + wid * 64) * 8]);
        }
        #pragma unroll
        for (int t = 0; t < (BN * 4) / 256; ++t) {
            int c = t * 256 + tid;
            GLD16(Bt + (size_t)(bn + (c >> 2)) * K + k0 + (c & 3) * 8,
                  &Bs[(t * 256 + wid * 64) * 8]);
        }
        __syncthreads();

        bf16x8 af[MI], bfr[NI];
        #pragma unroll
        for (int mi = 0; mi < MI; ++mi)
            af[mi] = __builtin_bit_cast(bf16x8,
                     *(const u16x8*)&As[(wr + mi * 16 + r0) * BK + kblk]);
        #pragma unroll
        for (int ni = 0; ni < NI; ++ni)
            bfr[ni] = __builtin_bit_cast(bf16x8,
                     *(const u16x8*)&Bs[(wc + ni * 16 + r0) * BK + kblk]);
        #pragma unroll
        for (int mi = 0; mi < MI; ++mi)
            #pragma unroll
            for (int ni = 0; ni < NI; ++ni)
                acc[mi][ni] = __builtin_amdgcn_mfma_f32_16x16x32_bf16(
                    af[mi], bfr[ni], acc[mi][ni], 0, 0, 0);
        __syncthreads();
    }

    const int r4 = (lane >> 4) * 4;
    #pragma unroll
    for (int mi = 0; mi < MI; ++mi)
        #pragma unroll
        for (int ni = 0; ni < NI; ++ni) {
            const int col = bn + wc + ni * 16 + r0;
            const float bb = bias[col];
            #pragma unroll
            for (int r = 0; r < 4; ++r) {
                const int row = bm + wr + mi * 16 + r4 + r;
                if (row < M) {
                    float v = acc[mi][ni][r] + bb;
                    if (RELU) v = fmaxf(v, 0.f);
                    if (SPLIT) {
                        if (col < 256) Cb[(size_t)row * DIM + col] = f2b(v);
                        else kvb[(size_t)row * 512 + (col - 256)] = fp8enc(v);
                    } else {
                        if (WF32)  Cf[(size_t)row * N + col] = v;
                        if (WBF16) Cb[(size_t)row * N + col] = f2b(v);
                    }
                }
            }
        }
}

// ---------------- attention v2: lane = (head-sub hs, neighbor j) ----------------
// Wave w handles heads 2w, 2w+1 concurrently. Score: full 32-dim dot per lane
// (paired fp8 decode). PV: lane = (hs, dim); per neighbor: readlane kidx ->
// SGPR base (scalar-pipe addressing), ds_bpermute p with imm offset.
__global__ __launch_bounds__(256) void attn_f8(const unsigned short* __restrict__ q,
                                               const unsigned char* __restrict__ kv,
                                               const int* __restrict__ samp,
                                               unsigned short* __restrict__ o)
{
    const int n = blockIdx.x;
    const int tid = threadIdx.x;
    const int wid = tid >> 6;
    const int lane = tid & 63;
    const int j = lane & 31;
    const int hs = lane >> 5;
    const int h = wid * 2 + hs;

    const int kidx = samp[n * KNEI + j];    // lanes j and 32+j both hold kidx_j

    // q for head h: 32 bf16 dims = 16 packed pairs (same addr across j-lanes)
    const uint4* qp = (const uint4*)(q + (size_t)n * DIM + h * HDIM);
    const uint4 qa = qp[0], qb = qp[1], qc = qp[2], qd = qp[3];
    const unsigned qw[16] = {qa.x, qa.y, qa.z, qa.w, qb.x, qb.y, qb.z, qb.w,
                             qc.x, qc.y, qc.z, qc.w, qd.x, qd.y, qd.z, qd.w};

    // k row slice for (neighbor j, head h): 32 fp8 bytes
    const unsigned char* krow = kv + (size_t)kidx * 512 + h * HDIM;
    const uint4 k0 = *(const uint4*)krow;
    const uint4 k1 = *(const uint4*)(krow + 16);
    const unsigned kw[8] = {k0.x, k0.y, k0.z, k0.w, k1.x, k1.y, k1.z, k1.w};

    float s = 0.f;
    #pragma unroll
    for (int i = 0; i < 8; ++i) {           // word i = dims 4i..4i+3
        f32x2 ka = fp8pk<false>(kw[i]);
        f32x2 kb = fp8pk<true>(kw[i]);
        unsigned q0 = qw[2 * i], q1 = qw[2 * i + 1];
        s = fmaf(blo(q0), ka.x, s);
        s = fmaf(bhi(q0), ka.y, s);
        s = fmaf(blo(q1), kb.x, s);
        s = fmaf(bhi(q1), kb.y, s);
    }
    s *= 0.17677669529663687f;              // 1/sqrt(32)

    // softmax over j within each 32-lane head group
    float m = s;
    #pragma unroll
    for (int sh = 16; sh; sh >>= 1) m = fmaxf(m, __shfl_xor(m, sh));
    float e = __expf(s - m);
    float sum = e;
    #pragma unroll
    for (int sh = 16; sh; sh >>= 1) sum += __shfl_xor(sum, sh);
    const float p = __fdividef(e, sum);

    // ---- PV: lane reinterpreted as (hs, d) ----
    const int d = j;                        // dim 0..31
    const int pbits = __builtin_bit_cast(int, p);
    const int pbase = hs * 128;             // byte addr of this head's p group
    const int voff = 256 + h * HDIM + d;    // v-slice offset within kv row
    float acc = 0.f;
    #pragma unroll
    for (int jj = 0; jj < KNEI; ++jj) {
        const int kj = __builtin_amdgcn_readlane(kidx, jj);       // SGPR
        const float pj = __builtin_bit_cast(float,
            __builtin_amdgcn_ds_bpermute(pbase + jj * 4, pbits)); // imm-offset pull
        const unsigned char* vp = kv + (size_t)kj * 512 + voff;
        acc = fmaf(pj, fp8dec<0>((unsigned)*vp), acc);
    }
    o[(size_t)n * DIM + h * HDIM + d] = f2b(acc);
}

// ---------------- fused residual add + LayerNorm ----------------
// XF32: residual input fp32 (else bf16). WFOUT: write fp32 out (else bf16 out).
template<int XF32, int WFOUT>
__global__ __launch_bounds__(256) void add_ln(const float* __restrict__ xf,
                                              const unsigned short* __restrict__ xb,
                                              const unsigned short* __restrict__ y,
                                              const float* __restrict__ gamma,
                                              const float* __restrict__ beta,
                                              float* __restrict__ outf,
                                              unsigned short* __restrict__ outb, int M)
{
    const int row = blockIdx.x * 4 + (threadIdx.x >> 6);
    const int lane = threadIdx.x & 63;
    if (row >= M) return;

    float s0, s1, s2, s3;
    if (XF32) {
        const float4 xv = *(const float4*)(xf + (size_t)row * DIM + lane * 4);
        s0 = xv.x; s1 = xv.y; s2 = xv.z; s3 = xv.w;
    } else {
        const u16x4 xv = *(const u16x4*)(xb + (size_t)row * DIM + lane * 4);
        s0 = b2f(xv[0]); s1 = b2f(xv[1]); s2 = b2f(xv[2]); s3 = b2f(xv[3]);
    }
    const u16x4 yv = *(const u16x4*)(y + (size_t)row * DIM + lane * 4);
    s0 += b2f(yv[0]); s1 += b2f(yv[1]); s2 += b2f(yv[2]); s3 += b2f(yv[3]);

    float sum = s0 + s1 + s2 + s3;
    float sq = s0 * s0 + s1 * s1 + s2 * s2 + s3 * s3;
    #pragma unroll
    for (int sh = 32; sh; sh >>= 1) {
        sum += __shfl_xor(sum, sh);
        sq  += __shfl_xor(sq, sh);
    }
    float mean = sum * (1.f / 256.f);
    float var = sq * (1.f / 256.f) - mean * mean;
    float rstd = rsqrtf(var + 1e-5f);

    const float4 gv = *(const float4*)(gamma + lane * 4);
    const float4 bv = *(const float4*)(beta + lane * 4);
    float o0 = (s0 - mean) * rstd * gv.x + bv.x;
    float o1 = (s1 - mean) * rstd * gv.y + bv.y;
    float o2 = (s2 - mean) * rstd * gv.z + bv.z;
    float o3 = (s3 - mean) * rstd * gv.w + bv.w;
    if (WFOUT) {
        float4 ov = { o0, o1, o2, o3 };
        *(float4*)(outf + (size_t)row * DIM + lane * 4) = ov;
    } else {
        u16x4 bb = { f2b(o0), f2b(o1), f2b(o2), f2b(o3) };
        *(u16x4*)(outb + (size_t)row * DIM + lane * 4) = bb;
    }
}

// ---------------- conversions ----------------
__global__ __launch_bounds__(256) void cvt_bf16(const float* __restrict__ in,
                                                unsigned short* __restrict__ out, int n4)
{
    int i = blockIdx.x * 256 + threadIdx.x;
    if (i < n4) {
        float4 v = ((const float4*)in)[i];
        u16x4 b = { f2b(v.x), f2b(v.y), f2b(v.z), f2b(v.w) };
        ((u16x4*)out)[i] = b;
    }
}

__global__ __launch_bounds__(256) void cvt_transpose(const float* __restrict__ W,
                                                     unsigned short* __restrict__ Wt,
                                                     int K, int N)
{
    __shared__ float t[32][33];
    const int n0 = blockIdx.x * 32, k0 = blockIdx.y * 32;
    const int tx = threadIdx.x & 31, ty = threadIdx.x >> 5;
    #pragma unroll
    for (int i = 0; i < 32; i += 8)
        t[ty + i][tx] = W[(size_t)(k0 + ty + i) * N + n0 + tx];
    __syncthreads();
    #pragma unroll
    for (int i = 0; i < 32; i += 8)
        Wt[(size_t)(n0 + ty + i) * K + k0 + tx] = f2b(t[tx][ty + i]);
}

// four 256x256 weights in one launch (blockIdx.z selects)
__global__ __launch_bounds__(256) void cvt_transpose4(const float* __restrict__ Wa,
                                                      const float* __restrict__ Wb,
                                                      const float* __restrict__ Wc,
                                                      const float* __restrict__ Wd,
                                                      unsigned short* __restrict__ Ta,
                                                      unsigned short* __restrict__ Tb,
                                                      unsigned short* __restrict__ Tc,
                                                      unsigned short* __restrict__ Td)
{
    const float* W; unsigned short* T;
    switch (blockIdx.z) {
        case 0:  W = Wa; T = Ta; break;
        case 1:  W = Wb; T = Tb; break;
        case 2:  W = Wc; T = Tc; break;
        default: W = Wd; T = Td; break;
    }
    __shared__ float t[32][33];
    const int n0 = blockIdx.x * 32, k0 = blockIdx.y * 32;
    const int tx = threadIdx.x & 31, ty = threadIdx.x >> 5;
    #pragma unroll
    for (int i = 0; i < 32; i += 8)
        t[ty + i][tx] = W[(size_t)(k0 + ty + i) * DIM + n0 + tx];
    __syncthreads();
    #pragma unroll
    for (int i = 0; i < 32; i += 8)
        T[(size_t)(n0 + ty + i) * DIM + k0 + tx] = f2b(t[tx][ty + i]);
}

__global__ void concat_bias(const float* a, const float* b, const float* c, float* out)
{
    int i = blockIdx.x * 256 + threadIdx.x;
    if (i < 256) out[i] = a[i];
    else if (i < 512) out[i] = b[i - 256];
    else if (i < 768) out[i] = c[i - 512];
}

extern "C" void kernel_launch(void* const* d_in, const int* in_sizes, int n_in,
                              void* d_out, int out_size, void* d_ws, size_t ws_size,
                              hipStream_t stream)
{
    const float* x    = (const float*)d_in[0];
    const int*   samp = (const int*)  d_in[1];
    const float* Wq = (const float*)d_in[2];  const float* bq = (const float*)d_in[3];
    const float* Wk = (const float*)d_in[4];  const float* bk = (const float*)d_in[5];
    const float* Wv = (const float*)d_in[6];  const float* bv = (const float*)d_in[7];
    const float* Wo = (const float*)d_in[8];  const float* bo = (const float*)d_in[9];
    const float* W1 = (const float*)d_in[10]; const float* b1 = (const float*)d_in[11];
    const float* W2 = (const float*)d_in[12]; const float* b2 = (const float*)d_in[13];
    const float* g1 = (const float*)d_in[14]; const float* be1 = (const float*)d_in[15];
    const float* g2 = (const float*)d_in[16]; const float* be2 = (const float*)d_in[17];
    float* out = (float*)d_out;

    char* w = (char*)d_ws;
    const size_t MB = 1u << 20;
    // weights (live whole launch): 0 .. 2 MB
    unsigned short* WqkvT = (unsigned short*)(w + 0);          // [768][256] bf16
    unsigned short* WoT   = (unsigned short*)(w + 393216);     // [256][256]
    unsigned short* W1T   = (unsigned short*)(w + 524288);     // [1024][256]
    unsigned short* W2T   = (unsigned short*)(w + 1048576);    // [256][1024]
    float*          bqkv  = (float*)(w + 1572864);             // [768]
    // activations — NON-OVERLAPPING liveness map:
    //   xb/ob  2..12.24MB | qb 13..23.24 | kvb 24..34.24 | attno 35..45.24
    //   x1b   46..56.24   | hmid 57..97.96
    unsigned short* xb    = (unsigned short*)(w + 2 * MB);     // [NN][256] bf16
    unsigned short* qb    = (unsigned short*)(w + 13 * MB);    // [NN][256] bf16
    unsigned char*  kvb   = (unsigned char*) (w + 24 * MB);    // [NN][512] fp8
    unsigned short* ob    = xb;                                // reuse xb (dead after QKV)
    unsigned short* attno = (unsigned short*)(w + 35 * MB);    // [NN][256] bf16
    unsigned short* x1b   = (unsigned short*)(w + 46 * MB);    // [NN][256] bf16; live to LN2
    unsigned short* hmid  = (unsigned short*)(w + 57 * MB);    // [NN][1024] bf16
    unsigned short* ffb   = attno;                             // reuse attno (dead after LN1)

    const dim3 blk(256);

    // ---- weight prep ----
    cvt_transpose4<<<dim3(8, 8, 4), blk, 0, stream>>>(
        Wq, Wk, Wv, Wo, WqkvT, WqkvT + 256 * 256, WqkvT + 512 * 256, WoT);
    cvt_transpose<<<dim3(32, 8), blk, 0, stream>>>(W1, W1T, DIM, DFFN);
    cvt_transpose<<<dim3(8, 32), blk, 0, stream>>>(W2, W2T, DFFN, DIM);
    concat_bias<<<dim3(3), blk, 0, stream>>>(bq, bk, bv, bqkv);
    cvt_bf16<<<dim3((NN * DIM / 4 + 255) / 256), blk, 0, stream>>>(x, xb, NN * DIM / 4);

    // ---- fused QKV projection: Q->bf16, K/V->fp8 ----
    gemm_mfma<128, 0, 0, 0, 1><<<dim3(157, 6), blk, 0, stream>>>(
        xb, WqkvT, bqkv, nullptr, qb, kvb, NN, QKVD, DIM);

    // ---- attention ----
    attn_f8<<<dim3(NN), blk, 0, stream>>>(qb, kvb, samp, ob);

    // ---- out proj -> bf16, residual(x f32)+LN1 -> bf16 ----
    gemm_mfma<64, 0, 0, 1, 0><<<dim3(313, 2), blk, 0, stream>>>(
        ob, WoT, bo, nullptr, attno, nullptr, NN, DIM, DIM);
    add_ln<1, 0><<<dim3(NN / 4), blk, 0, stream>>>(x, nullptr, attno, g1, be1,
                                                   nullptr, x1b, NN);

    // ---- FFN ----
    gemm_mfma<128, 1, 0, 1, 0><<<dim3(157, 8), blk, 0, stream>>>(
        x1b, W1T, b1, nullptr, hmid, nullptr, NN, DFFN, DIM);
    gemm_mfma<64, 0, 0, 1, 0><<<dim3(313, 2), blk, 0, stream>>>(
        hmid, W2T, b2, nullptr, ffb, nullptr, NN, DIM, DFFN);
    add_ln<0, 1><<<dim3(NN / 4), blk, 0, stream>>>(nullptr, x1b, ffb, g2, be2,
                                                   out, nullptr, NN);
}